// Round 4
// baseline (234.525 us; speedup 1.0000x reference)
//
#include <hip/hip_runtime.h>
#include <hip/hip_bf16.h>

// Problem constants (fixed by the reference file).
#define IMG_H 4096
#define IMG_W 4096
#define NPIX (IMG_H * IMG_W)

#define TILE 64
#define TILES_X (IMG_W / TILE)          // 64
#define TILES_Y (IMG_H / TILE)          // 64
#define NBINS (TILES_X * TILES_Y)       // 4096
#define BIN_CAP 256                     // lambda=49 boxes/bin; 256 is ~19 sigma

typedef float f4v __attribute__((ext_vector_type(4)));

static __device__ __forceinline__ void nt_store4(float* p, float a, float b,
                                                 float c, float d) {
    f4v v = {a, b, c, d};
    __builtin_nontemporal_store(v, (f4v*)p);
}

// ---------------------------------------------------------------------------
// Kernel 1: bin boxes by center pixel's 64x64 tile.
//   bins_meta: bits 0..17 box idx | 18..23 lx | 24..29 ly | 30 valid
//     (same pixel => same lx/ly/valid bits, so atomicMax(meta) picks the
//      highest box index == numpy last-write-wins)
//   bins_wh: the box's (w,h) payload, so nothing ever re-gathers boxes[].
// ---------------------------------------------------------------------------
__global__ __launch_bounds__(256) void bin_boxes_kernel(
    const float* __restrict__ boxes,
    int* __restrict__ counts,
    int* __restrict__ bins_meta,
    float2* __restrict__ bins_wh,
    int nboxes)
{
    int b = blockIdx.x * blockDim.x + threadIdx.x;
    if (b >= nboxes) return;
    float4 bx = reinterpret_cast<const float4*>(boxes)[b];
    int cx = (int)(bx.x * (float)IMG_W);
    int cy = (int)(bx.y * (float)IMG_H);
    int valid = (cx >= 1 && cx <= IMG_W - 2 && cy >= 1 && cy <= IMG_H - 2) ? 1 : 0;
    int pack = b | ((cx & 63) << 18) | ((cy & 63) << 24) | (valid << 30);
    int bin = (cy >> 6) * TILES_X + (cx >> 6);
    int slot = atomicAdd(&counts[bin], 1);
    if (slot < BIN_CAP) {
        bins_meta[bin * BIN_CAP + slot] = pack;
        bins_wh[bin * BIN_CAP + slot] = make_float2(bx.z, bx.w);
    }
}

// ---------------------------------------------------------------------------
// Kernel 2: one block per 64x64 tile.
//   replay:   own + 8 neighbor bins -> LDS center bitmap (1 atomicOr/box)
//             + own-bin winner atomicMax into lidx.
//   phase 2:  own-bin entries (<=256 -> one coalesced iteration) find their
//             match; barrier; winner overwrites lidx[px] with w's float bits.
//   epilogue A: heat from bitmap (shift/OR class masks: center m[4] >= edge
//             m[1] >= corner m[0]) + s0 from lidx; nontemporal float4 stores.
//   phase 3:  winner overwrites lidx[px] with h bits; epilogue B: s1.
//   All values exact fp32 end-to-end (absmax 0).
// ---------------------------------------------------------------------------
__global__ __launch_bounds__(256) void tile_kernel(
    const float* __restrict__ mount,
    const int* __restrict__ counts,
    const int* __restrict__ bins_meta,
    const float2* __restrict__ bins_wh,
    float* __restrict__ heat,
    float* __restrict__ s0,
    float* __restrict__ s1)
{
    __shared__ int lidx[TILE * TILE];         // 16 KB: meta -> w bits -> h bits
    __shared__ unsigned int bm[TILE + 2][4];  // 66 rows x 96 bits halo bitmap
    __shared__ int pfx[10];
    __shared__ int bbase[9];

    int tid = threadIdx.x;
    int tile = blockIdx.x;
    int tx = tile & (TILES_X - 1);
    int ty = tile >> 6;

    for (int i = tid; i < TILE * TILE; i += 256) lidx[i] = -1;
    for (int i = tid; i < (TILE + 2) * 4; i += 256) ((unsigned int*)bm)[i] = 0u;

    if (tid < 9) {
        int nty = ty + tid / 3 - 1;
        int ntx = tx + tid % 3 - 1;
        int cnt = 0, base = 0;
        if ((unsigned)nty < TILES_Y && (unsigned)ntx < TILES_X) {
            int bin = nty * TILES_X + ntx;
            cnt = min(counts[bin], BIN_CAP);
            base = bin * BIN_CAP;
        }
        pfx[tid + 1] = cnt;
        bbase[tid] = base;
        if (tid == 0) pfx[0] = 0;
    }
    __syncthreads();
    if (tid == 0) {
#pragma unroll
        for (int j = 0; j < 9; ++j) pfx[j + 1] += pfx[j];
    }
    __syncthreads();
    int S = pfx[9];

    // ---- replay: winner meta + center bitmap ----
    for (int i = tid; i < S; i += 256) {
        int j = 0;
        while (pfx[j + 1] <= i) ++j;
        int p = bins_meta[bbase[j] + (i - pfx[j])];
        int lx = (p >> 18) & 63;
        int ly = (p >> 24) & 63;
        if (j == 4) atomicMax(&lidx[ly * TILE + lx], p);
        if (p & (1 << 30)) {
            int Lx = lx + (j % 3) * 64 - 64;   // local coords in OUR tile
            int Ly = ly + (j / 3) * 64 - 64;
            if (Lx >= -1 && Lx <= TILE && Ly >= -1 && Ly <= TILE) {
                int pos = Lx + 1;              // 0..65
                atomicOr(&bm[Ly + 1][pos >> 5], 1u << (pos & 31));
            }
        }
    }
    __syncthreads();

    // ---- phase 2: own-bin winners pick up their (w,h) payload ----
    int cnt4 = pfx[5] - pfx[4];               // own-bin count (<= 256)
    bool match = false;
    int mypx = 0;
    float2 mywh = make_float2(0.f, 0.f);
    if (tid < cnt4) {
        int m = bins_meta[bbase[4] + tid];
        mywh = bins_wh[bbase[4] + tid];
        mypx = ((m >> 24) & 63) * TILE + ((m >> 18) & 63);
        match = (lidx[mypx] == m);            // unique winner per pixel
    }
    __syncthreads();                          // all compares before any write
    if (match) lidx[mypx] = __float_as_int(mywh.x);   // w bits (>= 0)
    __syncthreads();

    float mvC = mount[4];   // 1.0   (center)
    float mvE = mount[1];   // .6065 (edge)
    float mvK = mount[0];   // .3679 (corner)   mvC >= mvE >= mvK
    int ty0 = ty * TILE, tx0 = tx * TILE;

    // ---- epilogue A: heat + s0 ----
#pragma unroll
    for (int pass = 0; pass < 4; ++pass) {
        int idx = pass * 1024 + tid * 4;   // pixel index in tile
        int r = idx >> 6;
        int xb = idx & 63;

        uint4 w0 = *(const uint4*)&bm[r][0];
        uint4 w1 = *(const uint4*)&bm[r + 1][0];
        uint4 w2 = *(const uint4*)&bm[r + 2][0];
        unsigned long long V0 = ((unsigned long long)w0.y << 32) | w0.x;
        unsigned long long V1 = ((unsigned long long)w1.y << 32) | w1.x;
        unsigned long long V2 = ((unsigned long long)w2.y << 32) | w2.x;
        if (xb) {
            V0 = (V0 >> xb) | ((unsigned long long)w0.z << (64 - xb));
            V1 = (V1 >> xb) | ((unsigned long long)w1.z << (64 - xb));
            V2 = (V2 >> xb) | ((unsigned long long)w2.z << (64 - xb));
        }
        unsigned int C = (unsigned int)(V1 >> 1);
        unsigned int E = (unsigned int)V1 | (unsigned int)(V1 >> 2)
                       | (unsigned int)(V0 >> 1) | (unsigned int)(V2 >> 1);
        unsigned int K = (unsigned int)V0 | (unsigned int)(V0 >> 2)
                       | (unsigned int)V2 | (unsigned int)(V2 >> 2);

        float h[4];
#pragma unroll
        for (int jj = 0; jj < 4; ++jj) {
            float v = 0.f;
            if ((K >> jj) & 1) v = mvK;
            if ((E >> jj) & 1) v = mvE;
            if ((C >> jj) & 1) v = mvC;
            h[jj] = v;
        }

        int g = (ty0 + r) * IMG_W + tx0 + xb;
        nt_store4(&heat[g], h[0], h[1], h[2], h[3]);

        int4 iv = *reinterpret_cast<const int4*>(&lidx[idx]);
        nt_store4(&s0[g],
                  iv.x >= 0 ? __int_as_float(iv.x) : 0.f,
                  iv.y >= 0 ? __int_as_float(iv.y) : 0.f,
                  iv.z >= 0 ? __int_as_float(iv.z) : 0.f,
                  iv.w >= 0 ? __int_as_float(iv.w) : 0.f);
    }
    __syncthreads();

    // ---- phase 3 + epilogue B: s1 ----
    if (match) lidx[mypx] = __float_as_int(mywh.y);   // h bits (>= 0)
    __syncthreads();

#pragma unroll
    for (int pass = 0; pass < 4; ++pass) {
        int idx = pass * 1024 + tid * 4;
        int r = idx >> 6;
        int xb = idx & 63;
        int g = (ty0 + r) * IMG_W + tx0 + xb;
        int4 iv = *reinterpret_cast<const int4*>(&lidx[idx]);
        nt_store4(&s1[g],
                  iv.x >= 0 ? __int_as_float(iv.x) : 0.f,
                  iv.y >= 0 ? __int_as_float(iv.y) : 0.f,
                  iv.z >= 0 ? __int_as_float(iv.z) : 0.f,
                  iv.w >= 0 ? __int_as_float(iv.w) : 0.f);
    }
}

extern "C" void kernel_launch(void* const* d_in, const int* in_sizes, int n_in,
                              void* d_out, int out_size, void* d_ws, size_t ws_size,
                              hipStream_t stream) {
    const float* boxes = (const float*)d_in[0];   // [B,4] fp32
    const float* mount = (const float*)d_in[1];   // [3,3] fp32
    int nboxes = in_sizes[0] / 4;

    float* out  = (float*)d_out;
    float* heat = out;               // [1,1,H,W]
    float* s0   = out + NPIX;        // sizemap ch0 (w)
    float* s1   = out + 2 * NPIX;    // sizemap ch1 (h)

    // workspace layout (ws poisoned 0xAA each call):
    int*    counts    = (int*)d_ws;                       // 16 KB
    int*    bins_meta = counts + NBINS;                   // 4 MB
    float2* bins_wh   = (float2*)(bins_meta + NBINS * BIN_CAP);  // 8 MB

    hipMemsetAsync(counts, 0, NBINS * sizeof(int), stream);

    int bgrid = (nboxes + 255) / 256;
    bin_boxes_kernel<<<bgrid, 256, 0, stream>>>(boxes, counts, bins_meta,
                                                bins_wh, nboxes);

    tile_kernel<<<NBINS, 256, 0, stream>>>(mount, counts, bins_meta, bins_wh,
                                           heat, s0, s1);
}

// Round 5
// 223.282 us; speedup vs baseline: 1.0504x; 1.0504x over previous
//
#include <hip/hip_runtime.h>
#include <hip/hip_bf16.h>

// Problem constants (fixed by the reference file).
#define IMG_H 4096
#define IMG_W 4096
#define NPIX (IMG_H * IMG_W)

#define TILE 64
#define TILES_X (IMG_W / TILE)          // 64
#define TILES_Y (IMG_H / TILE)          // 64
#define NBINS (TILES_X * TILES_Y)       // 4096
#define BIN_CAP 256                     // lambda=49 boxes/bin; 256 is ~19 sigma

// ---------------------------------------------------------------------------
// Kernel 1: bin boxes by center pixel's 64x64 tile.
//   bins_meta: bits 0..17 box idx | 18..23 lx | 24..29 ly | 30 valid
//     (same pixel => same lx/ly/valid bits, so atomicMax(meta) picks the
//      highest box index == numpy last-write-wins)
//   bins_wh: the box's (w,h) payload, so nothing ever re-gathers boxes[].
// ---------------------------------------------------------------------------
__global__ __launch_bounds__(256) void bin_boxes_kernel(
    const float* __restrict__ boxes,
    int* __restrict__ counts,
    int* __restrict__ bins_meta,
    float2* __restrict__ bins_wh,
    int nboxes)
{
    int b = blockIdx.x * blockDim.x + threadIdx.x;
    if (b >= nboxes) return;
    float4 bx = reinterpret_cast<const float4*>(boxes)[b];
    int cx = (int)(bx.x * (float)IMG_W);
    int cy = (int)(bx.y * (float)IMG_H);
    int valid = (cx >= 1 && cx <= IMG_W - 2 && cy >= 1 && cy <= IMG_H - 2) ? 1 : 0;
    int pack = b | ((cx & 63) << 18) | ((cy & 63) << 24) | (valid << 30);
    int bin = (cy >> 6) * TILES_X + (cx >> 6);
    int slot = atomicAdd(&counts[bin], 1);
    if (slot < BIN_CAP) {
        bins_meta[bin * BIN_CAP + slot] = pack;
        bins_wh[bin * BIN_CAP + slot] = make_float2(bx.z, bx.w);
    }
}

// ---------------------------------------------------------------------------
// Kernel 2: one block per 64x64 tile.  (R3 structure + LDS payload deposit.)
//   replay:   own + 8 neighbor bins -> LDS center bitmap (1 atomicOr/box)
//             + own-bin winner atomicMax(meta) into lidx.
//   phase 2:  own-bin entries (<=256 -> one coalesced L2-hot iteration) test
//             lidx[px]==meta; barrier; the unique winner per occupied pixel
//             deposits w bits into lidx[px] and h bits into lh[px].
//   epilogue: ONE fused loop: heat from bitmap (center m[4] >= edge m[1] >=
//             corner m[0]) + s0/s1 from LDS; plain coalesced float4 stores.
//   All values exact fp32 end-to-end (absmax 0).
// ---------------------------------------------------------------------------
__global__ __launch_bounds__(256) void tile_kernel(
    const float* __restrict__ mount,
    const int* __restrict__ counts,
    const int* __restrict__ bins_meta,
    const float2* __restrict__ bins_wh,
    float* __restrict__ heat,
    float* __restrict__ s0,
    float* __restrict__ s1)
{
    __shared__ int lidx[TILE * TILE];         // 16 KB: meta, then w bits
    __shared__ int lh[TILE * TILE];           // 16 KB: h bits (winner-written)
    __shared__ unsigned int bm[TILE + 2][4];  // 66 rows x 96 bits halo bitmap
    __shared__ int pfx[10];
    __shared__ int bbase[9];

    int tid = threadIdx.x;
    int tile = blockIdx.x;
    int tx = tile & (TILES_X - 1);
    int ty = tile >> 6;

    for (int i = tid; i < TILE * TILE; i += 256) lidx[i] = -1;
    for (int i = tid; i < (TILE + 2) * 4; i += 256) ((unsigned int*)bm)[i] = 0u;

    if (tid < 9) {
        int nty = ty + tid / 3 - 1;
        int ntx = tx + tid % 3 - 1;
        int cnt = 0, base = 0;
        if ((unsigned)nty < TILES_Y && (unsigned)ntx < TILES_X) {
            int bin = nty * TILES_X + ntx;
            cnt = min(counts[bin], BIN_CAP);
            base = bin * BIN_CAP;
        }
        pfx[tid + 1] = cnt;
        bbase[tid] = base;
        if (tid == 0) pfx[0] = 0;
    }
    __syncthreads();
    if (tid == 0) {
#pragma unroll
        for (int j = 0; j < 9; ++j) pfx[j + 1] += pfx[j];
    }
    __syncthreads();
    int S = pfx[9];

    // ---- replay: winner meta + center bitmap ----
    for (int i = tid; i < S; i += 256) {
        int j = 0;
        while (pfx[j + 1] <= i) ++j;
        int p = bins_meta[bbase[j] + (i - pfx[j])];
        int lx = (p >> 18) & 63;
        int ly = (p >> 24) & 63;
        if (j == 4) atomicMax(&lidx[ly * TILE + lx], p);
        if (p & (1 << 30)) {
            int Lx = lx + (j % 3) * 64 - 64;   // local coords in OUR tile
            int Ly = ly + (j / 3) * 64 - 64;
            if (Lx >= -1 && Lx <= TILE && Ly >= -1 && Ly <= TILE) {
                int pos = Lx + 1;              // 0..65
                atomicOr(&bm[Ly + 1][pos >> 5], 1u << (pos & 31));
            }
        }
    }
    __syncthreads();

    // ---- phase 2: unique winner per occupied pixel deposits (w,h) bits ----
    int cnt4 = pfx[5] - pfx[4];               // own-bin count (<= 256)
    bool match = false;
    int mypx = 0;
    float2 mywh = make_float2(0.f, 0.f);
    if (tid < cnt4) {
        int m = bins_meta[bbase[4] + tid];
        mywh = bins_wh[bbase[4] + tid];
        mypx = ((m >> 24) & 63) * TILE + ((m >> 18) & 63);
        match = (lidx[mypx] == m);
    }
    __syncthreads();                          // all compares before any write
    if (match) {
        lidx[mypx] = __float_as_int(mywh.x);  // w bits (>= 0; empty stays -1)
        lh[mypx]   = __float_as_int(mywh.y);  // h bits
    }
    __syncthreads();

    float mvC = mount[4];   // 1.0   (center)
    float mvE = mount[1];   // .6065 (edge)
    float mvK = mount[0];   // .3679 (corner)   mvC >= mvE >= mvK
    int ty0 = ty * TILE, tx0 = tx * TILE;

    // ---- fused epilogue: heat + s0 + s1, once per pixel ----
#pragma unroll
    for (int pass = 0; pass < 4; ++pass) {
        int idx = pass * 1024 + tid * 4;   // pixel index in tile
        int r = idx >> 6;
        int xb = idx & 63;

        uint4 w0 = *(const uint4*)&bm[r][0];
        uint4 w1 = *(const uint4*)&bm[r + 1][0];
        uint4 w2 = *(const uint4*)&bm[r + 2][0];
        unsigned long long V0 = ((unsigned long long)w0.y << 32) | w0.x;
        unsigned long long V1 = ((unsigned long long)w1.y << 32) | w1.x;
        unsigned long long V2 = ((unsigned long long)w2.y << 32) | w2.x;
        if (xb) {
            V0 = (V0 >> xb) | ((unsigned long long)w0.z << (64 - xb));
            V1 = (V1 >> xb) | ((unsigned long long)w1.z << (64 - xb));
            V2 = (V2 >> xb) | ((unsigned long long)w2.z << (64 - xb));
        }
        unsigned int C = (unsigned int)(V1 >> 1);
        unsigned int E = (unsigned int)V1 | (unsigned int)(V1 >> 2)
                       | (unsigned int)(V0 >> 1) | (unsigned int)(V2 >> 1);
        unsigned int K = (unsigned int)V0 | (unsigned int)(V0 >> 2)
                       | (unsigned int)V2 | (unsigned int)(V2 >> 2);

        float h[4];
#pragma unroll
        for (int jj = 0; jj < 4; ++jj) {
            float v = 0.f;
            if ((K >> jj) & 1) v = mvK;
            if ((E >> jj) & 1) v = mvE;
            if ((C >> jj) & 1) v = mvC;
            h[jj] = v;
        }

        int g = (ty0 + r) * IMG_W + tx0 + xb;
        *reinterpret_cast<float4*>(&heat[g]) = make_float4(h[0], h[1], h[2], h[3]);

        int4 iw = *reinterpret_cast<const int4*>(&lidx[idx]);
        int4 ih = *reinterpret_cast<const int4*>(&lh[idx]);
        *reinterpret_cast<float4*>(&s0[g]) = make_float4(
            iw.x >= 0 ? __int_as_float(iw.x) : 0.f,
            iw.y >= 0 ? __int_as_float(iw.y) : 0.f,
            iw.z >= 0 ? __int_as_float(iw.z) : 0.f,
            iw.w >= 0 ? __int_as_float(iw.w) : 0.f);
        *reinterpret_cast<float4*>(&s1[g]) = make_float4(
            iw.x >= 0 ? __int_as_float(ih.x) : 0.f,
            iw.y >= 0 ? __int_as_float(ih.y) : 0.f,
            iw.z >= 0 ? __int_as_float(ih.z) : 0.f,
            iw.w >= 0 ? __int_as_float(ih.w) : 0.f);
    }
}

extern "C" void kernel_launch(void* const* d_in, const int* in_sizes, int n_in,
                              void* d_out, int out_size, void* d_ws, size_t ws_size,
                              hipStream_t stream) {
    const float* boxes = (const float*)d_in[0];   // [B,4] fp32
    const float* mount = (const float*)d_in[1];   // [3,3] fp32
    int nboxes = in_sizes[0] / 4;

    float* out  = (float*)d_out;
    float* heat = out;               // [1,1,H,W]
    float* s0   = out + NPIX;        // sizemap ch0 (w)
    float* s1   = out + 2 * NPIX;    // sizemap ch1 (h)

    // workspace layout (ws poisoned 0xAA each call):
    int*    counts    = (int*)d_ws;                       // 16 KB
    int*    bins_meta = counts + NBINS;                   // 4 MB
    float2* bins_wh   = (float2*)(bins_meta + NBINS * BIN_CAP);  // 8 MB

    hipMemsetAsync(counts, 0, NBINS * sizeof(int), stream);

    int bgrid = (nboxes + 255) / 256;
    bin_boxes_kernel<<<bgrid, 256, 0, stream>>>(boxes, counts, bins_meta,
                                                bins_wh, nboxes);

    tile_kernel<<<NBINS, 256, 0, stream>>>(mount, counts, bins_meta, bins_wh,
                                           heat, s0, s1);
}

// Round 7
// 223.138 us; speedup vs baseline: 1.0510x; 1.0006x over previous
//
#include <hip/hip_runtime.h>
#include <hip/hip_bf16.h>

// Problem constants (fixed by the reference file).
#define IMG_H 4096
#define IMG_W 4096
#define NPIX (IMG_H * IMG_W)

#define TILE 64
#define TILES_X (IMG_W / TILE)          // 64
#define TILES_Y (IMG_H / TILE)          // 64
#define NBINS (TILES_X * TILES_Y)       // 4096
#define BIN_CAP 256                     // lambda=49 boxes/bin; 256 is ~19 sigma

// ---------------------------------------------------------------------------
// Kernel 1: bin boxes by center pixel's 64x64 tile.
//   bins_meta: bits 0..17 box idx | 18..23 lx | 24..29 ly | 30 valid
//   bins_wh:   the box's (w,h) payload (per-bin 2 KB contiguous segment).
// ---------------------------------------------------------------------------
__global__ __launch_bounds__(256) void bin_boxes_kernel(
    const float* __restrict__ boxes,
    int* __restrict__ counts,
    int* __restrict__ bins_meta,
    float2* __restrict__ bins_wh,
    int nboxes)
{
    int b = blockIdx.x * blockDim.x + threadIdx.x;
    if (b >= nboxes) return;
    float4 bx = reinterpret_cast<const float4*>(boxes)[b];
    int cx = (int)(bx.x * (float)IMG_W);
    int cy = (int)(bx.y * (float)IMG_H);
    int valid = (cx >= 1 && cx <= IMG_W - 2 && cy >= 1 && cy <= IMG_H - 2) ? 1 : 0;
    int pack = b | ((cx & 63) << 18) | ((cy & 63) << 24) | (valid << 30);
    int bin = (cy >> 6) * TILES_X + (cx >> 6);
    int slot = atomicAdd(&counts[bin], 1);
    if (slot < BIN_CAP) {
        bins_meta[bin * BIN_CAP + slot] = pack;
        bins_wh[bin * BIN_CAP + slot] = make_float2(bx.z, bx.w);
    }
}

// ---------------------------------------------------------------------------
// Kernel 2: one block per 64x64 tile. LDS = 17.1 KB -> 8 blocks/CU
// (thread-limited), exactly 2 barriers.
//   replay:   own + 8 neighbor bins (per-thread register prefix over
//             wave-uniform counts loads) -> LDS center bitmap (1 atomicOr per
//             valid box) + own-bin winner atomicMax of (boxidx<<8 | slot).
//             Ordering is by box idx (slot is a dead tiebreak: same pixel
//             never holds the same box twice) == numpy last-write-wins.
//   epilogue: heat from bitmap (center m[4] >= edge m[1] >= corner m[0],
//             exact fp32 pass-through) + s0/s1 via slot-gather from the
//             block's own 2 KB bins_wh segment (winner lanes only, ~1.2%).
//   NOTE: bm has (TILE+2)*4 = 264 words > 256 threads -> init MUST be the
//   strided loop (R6's `if (tid < 264)` left 8 poisoned words: absmax 1.0).
// ---------------------------------------------------------------------------
__global__ __launch_bounds__(256) void tile_kernel(
    const float* __restrict__ mount,
    const int* __restrict__ counts,
    const int* __restrict__ bins_meta,
    const float2* __restrict__ bins_wh,
    float* __restrict__ heat,
    float* __restrict__ s0,
    float* __restrict__ s1)
{
    __shared__ int lidx[TILE * TILE];         // 16 KB: (boxidx<<8)|slot
    __shared__ unsigned int bm[TILE + 2][4];  // 66 rows x 96 bits halo bitmap

    int tid = threadIdx.x;
    int tile = blockIdx.x;
    int tx = tile & (TILES_X - 1);
    int ty = tile >> 6;

    for (int i = tid; i < TILE * TILE; i += 256) lidx[i] = -1;
    for (int i = tid; i < (TILE + 2) * 4; i += 256) ((unsigned int*)bm)[i] = 0u;

    // per-thread (wave-uniform -> scalar) 9-bin counts + register prefix sum
    int cnt[9], base[9];
#pragma unroll
    for (int j = 0; j < 9; ++j) {
        int nty = ty + j / 3 - 1;
        int ntx = tx + j % 3 - 1;
        bool ok = ((unsigned)nty < TILES_Y) & ((unsigned)ntx < TILES_X);
        int bin = nty * TILES_X + ntx;
        base[j] = bin * BIN_CAP;
        cnt[j] = ok ? min(counts[bin], BIN_CAP) : 0;
    }
    int pfx[10];
    pfx[0] = 0;
#pragma unroll
    for (int j = 0; j < 9; ++j) pfx[j + 1] = pfx[j] + cnt[j];
    int S = pfx[9];
    __syncthreads();   // LDS zero-init complete

    // ---- replay: winner word + center bitmap ----
    for (int i = tid; i < S; i += 256) {
        int j = 0;
#pragma unroll
        for (int k = 1; k < 9; ++k) j += (i >= pfx[k]);
        int rel = i - pfx[j];
        int p = bins_meta[base[j] + rel];
        int lx = (p >> 18) & 63;
        int ly = (p >> 24) & 63;
        if (j == 4) {
            // rel == slot in own bin
            atomicMax(&lidx[ly * TILE + lx], ((p & 0x3FFFF) << 8) | rel);
        }
        if (p & (1 << 30)) {
            int Lx = lx + (j % 3) * 64 - 64;   // local coords in OUR tile
            int Ly = ly + (j / 3) * 64 - 64;
            if (Lx >= -1 && Lx <= TILE && Ly >= -1 && Ly <= TILE) {
                int pos = Lx + 1;              // 0..65
                atomicOr(&bm[Ly + 1][pos >> 5], 1u << (pos & 31));
            }
        }
    }
    __syncthreads();

    float mvC = mount[4];   // 1.0   (center)
    float mvE = mount[1];   // .6065 (edge)
    float mvK = mount[0];   // .3679 (corner)   mvC >= mvE >= mvK
    int ty0 = ty * TILE, tx0 = tx * TILE;
    const float2* mywh = &bins_wh[tile * BIN_CAP];   // own-bin 2 KB segment

    // ---- fused epilogue: heat + s0 + s1, once per pixel ----
#pragma unroll
    for (int pass = 0; pass < 4; ++pass) {
        int idx = pass * 1024 + tid * 4;   // pixel index in tile
        int r = idx >> 6;
        int xb = idx & 63;

        uint4 w0 = *(const uint4*)&bm[r][0];
        uint4 w1 = *(const uint4*)&bm[r + 1][0];
        uint4 w2 = *(const uint4*)&bm[r + 2][0];
        unsigned long long V0 = ((unsigned long long)w0.y << 32) | w0.x;
        unsigned long long V1 = ((unsigned long long)w1.y << 32) | w1.x;
        unsigned long long V2 = ((unsigned long long)w2.y << 32) | w2.x;
        if (xb) {
            V0 = (V0 >> xb) | ((unsigned long long)w0.z << (64 - xb));
            V1 = (V1 >> xb) | ((unsigned long long)w1.z << (64 - xb));
            V2 = (V2 >> xb) | ((unsigned long long)w2.z << (64 - xb));
        }
        unsigned int C = (unsigned int)(V1 >> 1);
        unsigned int E = (unsigned int)V1 | (unsigned int)(V1 >> 2)
                       | (unsigned int)(V0 >> 1) | (unsigned int)(V2 >> 1);
        unsigned int K = (unsigned int)V0 | (unsigned int)(V0 >> 2)
                       | (unsigned int)V2 | (unsigned int)(V2 >> 2);

        float h[4];
#pragma unroll
        for (int jj = 0; jj < 4; ++jj) {
            float v = 0.f;
            if ((K >> jj) & 1) v = mvK;
            if ((E >> jj) & 1) v = mvE;
            if ((C >> jj) & 1) v = mvC;
            h[jj] = v;
        }

        int g = (ty0 + r) * IMG_W + tx0 + xb;
        *reinterpret_cast<float4*>(&heat[g]) = make_float4(h[0], h[1], h[2], h[3]);

        int4 iw = *reinterpret_cast<const int4*>(&lidx[idx]);
        float4 ow = make_float4(0.f, 0.f, 0.f, 0.f);
        float4 oh = make_float4(0.f, 0.f, 0.f, 0.f);
        if (iw.x >= 0) { float2 wh = mywh[iw.x & 255]; ow.x = wh.x; oh.x = wh.y; }
        if (iw.y >= 0) { float2 wh = mywh[iw.y & 255]; ow.y = wh.x; oh.y = wh.y; }
        if (iw.z >= 0) { float2 wh = mywh[iw.z & 255]; ow.z = wh.x; oh.z = wh.y; }
        if (iw.w >= 0) { float2 wh = mywh[iw.w & 255]; ow.w = wh.x; oh.w = wh.y; }
        *reinterpret_cast<float4*>(&s0[g]) = ow;
        *reinterpret_cast<float4*>(&s1[g]) = oh;
    }
}

extern "C" void kernel_launch(void* const* d_in, const int* in_sizes, int n_in,
                              void* d_out, int out_size, void* d_ws, size_t ws_size,
                              hipStream_t stream) {
    const float* boxes = (const float*)d_in[0];   // [B,4] fp32
    const float* mount = (const float*)d_in[1];   // [3,3] fp32
    int nboxes = in_sizes[0] / 4;

    float* out  = (float*)d_out;
    float* heat = out;               // [1,1,H,W]
    float* s0   = out + NPIX;        // sizemap ch0 (w)
    float* s1   = out + 2 * NPIX;    // sizemap ch1 (h)

    // workspace layout (ws poisoned 0xAA each call):
    int*    counts    = (int*)d_ws;                       // 16 KB
    int*    bins_meta = counts + NBINS;                   // 4 MB
    float2* bins_wh   = (float2*)(bins_meta + NBINS * BIN_CAP);  // 8 MB

    hipMemsetAsync(counts, 0, NBINS * sizeof(int), stream);

    int bgrid = (nboxes + 255) / 256;
    bin_boxes_kernel<<<bgrid, 256, 0, stream>>>(boxes, counts, bins_meta,
                                                bins_wh, nboxes);

    tile_kernel<<<NBINS, 256, 0, stream>>>(mount, counts, bins_meta, bins_wh,
                                           heat, s0, s1);
}

// Round 8
// 222.230 us; speedup vs baseline: 1.0553x; 1.0041x over previous
//
#include <hip/hip_runtime.h>
#include <hip/hip_bf16.h>

// Problem constants (fixed by the reference file).
#define IMG_H 4096
#define IMG_W 4096
#define NPIX (IMG_H * IMG_W)

#define TILE 64
#define TILES_X (IMG_W / TILE)          // 64
#define TILES_Y (IMG_H / TILE)          // 64
#define NBINS (TILES_X * TILES_Y)       // 4096
#define BIN_CAP 256                     // lambda~52/bin incl replicas; ~14 sigma

// ---------------------------------------------------------------------------
// Kernel 1: bin boxes by center pixel's 64x64 tile, ONE int4 entry per box:
//   .x meta: idx(0..17) | lx<<18 | ly<<24 | valid<<30        (bit31 = 0)
//   .y = w bits, .z = h bits
// Border replication: a valid stamp crosses into a neighbor tile only when
// lx in {0,63} or ly in {0,63} (~6% of boxes). For those, append a
// STAMP-ONLY replica into the 1-3 affected neighbor bins:
//   .x meta: 0x80000000 | lxp(0..65) | lyp<<7   (lxp/lyp = halo coords + 1)
// Validity (1<=cx<=4094, 1<=cy<=4094) guarantees the target neighbor exists.
// Tiles then replay ONLY their own bin.
// ---------------------------------------------------------------------------
__global__ __launch_bounds__(256) void bin_boxes_kernel(
    const float* __restrict__ boxes,
    int* __restrict__ counts,
    int4* __restrict__ bins4,
    int nboxes)
{
    int b = blockIdx.x * blockDim.x + threadIdx.x;
    if (b >= nboxes) return;
    float4 bx = reinterpret_cast<const float4*>(boxes)[b];
    int cx = (int)(bx.x * (float)IMG_W);
    int cy = (int)(bx.y * (float)IMG_H);
    int lx = cx & 63, ly = cy & 63;
    int tx = cx >> 6, ty = cy >> 6;
    int valid = (cx >= 1 && cx <= IMG_W - 2 && cy >= 1 && cy <= IMG_H - 2) ? 1 : 0;

    int meta = b | (lx << 18) | (ly << 24) | (valid << 30);
    int bin = ty * TILES_X + tx;
    int slot = atomicAdd(&counts[bin], 1);
    if (slot < BIN_CAP)
        bins4[bin * BIN_CAP + slot] =
            make_int4(meta, __float_as_int(bx.z), __float_as_int(bx.w), 0);

    if (valid) {
        int dx = (lx == 0) ? -1 : (lx == 63 ? 1 : 0);
        int dy = (ly == 0) ? -1 : (ly == 63 ? 1 : 0);
        if (dx | dy) {
#pragma unroll
            for (int k = 0; k < 3; ++k) {
                int rdx = (k == 0 || k == 2) ? dx : 0;
                int rdy = (k == 1 || k == 2) ? dy : 0;
                if ((k == 0 && dx == 0) || (k == 1 && dy == 0) ||
                    (k == 2 && (dx == 0 || dy == 0))) continue;
                int nbin = (ty + rdy) * TILES_X + (tx + rdx);
                int lxp = lx - 64 * rdx + 1;   // 0..65 in neighbor's halo coords
                int lyp = ly - 64 * rdy + 1;
                int rmeta = 0x80000000 | lxp | (lyp << 7);
                int rslot = atomicAdd(&counts[nbin], 1);
                if (rslot < BIN_CAP)
                    bins4[nbin * BIN_CAP + rslot] = make_int4(rmeta, 0, 0, 0);
            }
        }
    }
}

// ---------------------------------------------------------------------------
// Kernel 2: one block per 64x64 tile. LDS 17.1 KB -> 8 blocks/CU, 2 barriers.
//   replay:   OWN bin only (~52 entries incl replicas -> one partial
//             iteration, coalesced int4 loads). Regular entry: atomicMax of
//             (idx<<8|slot) into lidx (box-idx ordering == numpy
//             last-write-wins; slot is a dead tiebreak) + bitmap OR if valid.
//             Replica (meta<0): bitmap OR only at halo coords.
//   epilogue: heat from bitmap (center m[4] >= edge m[1] >= corner m[0],
//             exact fp32 pass-through) + s0/s1 via slot-gather from the
//             block's own L1-hot bins4 segment (winner lanes only, ~1.2%).
//   NOTE: bm init must be the strided loop — 264 words > 256 threads (R6 bug).
// ---------------------------------------------------------------------------
__global__ __launch_bounds__(256) void tile_kernel(
    const float* __restrict__ mount,
    const int* __restrict__ counts,
    const int4* __restrict__ bins4,
    float* __restrict__ heat,
    float* __restrict__ s0,
    float* __restrict__ s1)
{
    __shared__ int lidx[TILE * TILE];         // 16 KB: (boxidx<<8)|slot
    __shared__ unsigned int bm[TILE + 2][4];  // 66 rows x 96 bits halo bitmap

    int tid = threadIdx.x;
    int tile = blockIdx.x;
    int tx = tile & (TILES_X - 1);
    int ty = tile >> 6;

    for (int i = tid; i < TILE * TILE; i += 256) lidx[i] = -1;
    for (int i = tid; i < (TILE + 2) * 4; i += 256) ((unsigned int*)bm)[i] = 0u;

    const int4* mybin = &bins4[tile * BIN_CAP];
    int mycnt = min(counts[tile], BIN_CAP);   // wave-uniform scalar load
    __syncthreads();   // LDS zero-init complete

    // ---- replay: own bin only ----
    for (int i = tid; i < mycnt; i += 256) {
        int p = mybin[i].x;
        if (p >= 0) {
            int lx = (p >> 18) & 63;
            int ly = (p >> 24) & 63;
            atomicMax(&lidx[ly * TILE + lx], ((p & 0x3FFFF) << 8) | i);
            if (p & (1 << 30)) {
                int pos = lx + 1;
                atomicOr(&bm[ly + 1][pos >> 5], 1u << (pos & 31));
            }
        } else {
            int lxp = p & 127;          // 0..65
            int lyp = (p >> 7) & 127;   // 0..65
            atomicOr(&bm[lyp][lxp >> 5], 1u << (lxp & 31));
        }
    }
    __syncthreads();

    float mvC = mount[4];   // 1.0   (center)
    float mvE = mount[1];   // .6065 (edge)
    float mvK = mount[0];   // .3679 (corner)   mvC >= mvE >= mvK
    int ty0 = ty * TILE, tx0 = tx * TILE;

    // ---- fused epilogue: heat + s0 + s1, once per pixel ----
#pragma unroll
    for (int pass = 0; pass < 4; ++pass) {
        int idx = pass * 1024 + tid * 4;   // pixel index in tile
        int r = idx >> 6;
        int xb = idx & 63;

        uint4 w0 = *(const uint4*)&bm[r][0];
        uint4 w1 = *(const uint4*)&bm[r + 1][0];
        uint4 w2 = *(const uint4*)&bm[r + 2][0];
        unsigned long long V0 = ((unsigned long long)w0.y << 32) | w0.x;
        unsigned long long V1 = ((unsigned long long)w1.y << 32) | w1.x;
        unsigned long long V2 = ((unsigned long long)w2.y << 32) | w2.x;
        if (xb) {
            V0 = (V0 >> xb) | ((unsigned long long)w0.z << (64 - xb));
            V1 = (V1 >> xb) | ((unsigned long long)w1.z << (64 - xb));
            V2 = (V2 >> xb) | ((unsigned long long)w2.z << (64 - xb));
        }
        unsigned int C = (unsigned int)(V1 >> 1);
        unsigned int E = (unsigned int)V1 | (unsigned int)(V1 >> 2)
                       | (unsigned int)(V0 >> 1) | (unsigned int)(V2 >> 1);
        unsigned int K = (unsigned int)V0 | (unsigned int)(V0 >> 2)
                       | (unsigned int)V2 | (unsigned int)(V2 >> 2);

        float h[4];
#pragma unroll
        for (int jj = 0; jj < 4; ++jj) {
            float v = 0.f;
            if ((K >> jj) & 1) v = mvK;
            if ((E >> jj) & 1) v = mvE;
            if ((C >> jj) & 1) v = mvC;
            h[jj] = v;
        }

        int g = (ty0 + r) * IMG_W + tx0 + xb;
        *reinterpret_cast<float4*>(&heat[g]) = make_float4(h[0], h[1], h[2], h[3]);

        int4 iw = *reinterpret_cast<const int4*>(&lidx[idx]);
        float4 ow = make_float4(0.f, 0.f, 0.f, 0.f);
        float4 oh = make_float4(0.f, 0.f, 0.f, 0.f);
        if (iw.x >= 0) { int4 e = mybin[iw.x & 255]; ow.x = __int_as_float(e.y); oh.x = __int_as_float(e.z); }
        if (iw.y >= 0) { int4 e = mybin[iw.y & 255]; ow.y = __int_as_float(e.y); oh.y = __int_as_float(e.z); }
        if (iw.z >= 0) { int4 e = mybin[iw.z & 255]; ow.z = __int_as_float(e.y); oh.z = __int_as_float(e.z); }
        if (iw.w >= 0) { int4 e = mybin[iw.w & 255]; ow.w = __int_as_float(e.y); oh.w = __int_as_float(e.z); }
        *reinterpret_cast<float4*>(&s0[g]) = ow;
        *reinterpret_cast<float4*>(&s1[g]) = oh;
    }
}

extern "C" void kernel_launch(void* const* d_in, const int* in_sizes, int n_in,
                              void* d_out, int out_size, void* d_ws, size_t ws_size,
                              hipStream_t stream) {
    const float* boxes = (const float*)d_in[0];   // [B,4] fp32
    const float* mount = (const float*)d_in[1];   // [3,3] fp32
    int nboxes = in_sizes[0] / 4;

    float* out  = (float*)d_out;
    float* heat = out;               // [1,1,H,W]
    float* s0   = out + NPIX;        // sizemap ch0 (w)
    float* s1   = out + 2 * NPIX;    // sizemap ch1 (h)

    // workspace layout (ws poisoned 0xAA each call):
    int*  counts = (int*)d_ws;                 // 16 KB
    int4* bins4  = (int4*)(counts + NBINS);    // 16 MB

    hipMemsetAsync(counts, 0, NBINS * sizeof(int), stream);

    int bgrid = (nboxes + 255) / 256;
    bin_boxes_kernel<<<bgrid, 256, 0, stream>>>(boxes, counts, bins4, nboxes);

    tile_kernel<<<NBINS, 256, 0, stream>>>(mount, counts, bins4, heat, s0, s1);
}